// Round 2
// baseline (1279.218 us; speedup 1.0000x reference)
//
#include <hip/hip_runtime.h>
#include <math.h>

#define B_ 8
#define C_ 64
#define H_ 128
#define W_ 128
#define O_ 64
#define HW (H_*W_)
#define KK 9

typedef float f32x4 __attribute__((ext_vector_type(4)));
typedef short s16x8 __attribute__((ext_vector_type(8)));

// ws layout (float offsets)
#define OFF_BUF  0
#define MASK_BUF (B_*18*HW)            // 2359296
#define WA_BUF   (MASK_BUF + B_*9*HW)  // 3538944
#define WBF_BUF  (WA_BUF + C_*KK*32)   // 3557376 ; 36864 ushorts (73728 B) of bf16 B-fragments

__device__ __forceinline__ unsigned short f2bf(float f) {
    union { float f; unsigned u; } v; v.f = f;
    unsigned r = (v.u + 0x7FFFu + ((v.u >> 16) & 1u)) >> 16;  // RNE
    return (unsigned short)r;
}

// wA[c][k][32]: fp32, oc 0..17 offset_w, 18..26 mod_w (for conv_a scalar-path reads)
// wbf: bf16 B-fragments for deform MFMA, layout [tap][ks][nt][lane][8j]:
//   B[k=c][n=o] with c = ks*32 + (lane>>4)*8 + j, o = nt*16 + (lane&15)
__global__ void prep_weights(const float* __restrict__ offw,
                             const float* __restrict__ modw,
                             const float* __restrict__ w,
                             float* __restrict__ ws) {
    int t = blockIdx.x * 256 + threadIdx.x;
    const int nA = C_ * KK * 32;
    if (t < nA) {
        int oc = t & 31;
        int ck = t >> 5;
        int c = ck / KK, k = ck % KK;
        float v = 0.f;
        if (oc < 18)      v = offw[oc * (C_ * KK) + c * KK + k];
        else if (oc < 27) v = modw[(oc - 18) * (C_ * KK) + c * KK + k];
        ws[WA_BUF + t] = v;
    } else {
        int t2 = t - nA;
        if (t2 < KK * 2 * 4 * 64 * 8) {
            int j    = t2 & 7;
            int lane = (t2 >> 3) & 63;
            int nt   = (t2 >> 9) & 3;
            int ks   = (t2 >> 11) & 1;
            int tap  = t2 >> 12;
            int c = ks * 32 + ((lane >> 4) & 3) * 8 + j;
            int o = nt * 16 + (lane & 15);
            float v = w[o * (C_ * KK) + c * KK + tap];
            ((unsigned short*)(ws + WBF_BUF))[t2] = f2bf(v);
        }
    }
}

// 3x3 conv, 27 outputs. 4 threads per pixel (16 channels each) + shfl_xor reduce.
__global__ __launch_bounds__(256) void conv_a(const float* __restrict__ x,
                                              const float* __restrict__ offb,
                                              const float* __restrict__ modb,
                                              float* __restrict__ ws) {
    int t = threadIdx.x;
    int csub = t & 3;
    int pid = t >> 2;                 // 0..63 pixels per block
    int tx = pid & 15, ty = pid >> 4; // 16 x 4 tile
    int b = blockIdx.z;
    int xx = blockIdx.x * 16 + tx;
    int yy = blockIdx.y * 4 + ty;

    float acc[27];
    if (csub == 0) {
#pragma unroll
        for (int oc = 0; oc < 18; oc++) acc[oc] = offb[oc];
#pragma unroll
        for (int oc = 0; oc < 9; oc++)  acc[18 + oc] = modb[oc];
    } else {
#pragma unroll
        for (int oc = 0; oc < 27; oc++) acc[oc] = 0.f;
    }

    int idx[9];
    float fl[9];
#pragma unroll
    for (int ky = 0; ky < 3; ky++)
#pragma unroll
        for (int kx = 0; kx < 3; kx++) {
            int yo = yy + ky - 1, xo = xx + kx - 1;
            bool v = (yo >= 0) && (yo < H_) && (xo >= 0) && (xo < W_);
            int yc = min(max(yo, 0), H_ - 1);
            int xc = min(max(xo, 0), W_ - 1);
            idx[ky * 3 + kx] = yc * W_ + xc;
            fl[ky * 3 + kx] = v ? 1.f : 0.f;
        }

    const float* xb = x + (size_t)b * C_ * HW + (size_t)(csub * 16) * HW;
    const float* wA = ws + WA_BUF + (csub * 16) * 9 * 32;

    for (int ci = 0; ci < 16; ci++) {
        float xv[9];
#pragma unroll
        for (int k = 0; k < 9; k++) xv[k] = xb[ci * HW + idx[k]] * fl[k];
#pragma unroll
        for (int k = 0; k < 9; k++) {
            const float* wr = wA + (ci * 9 + k) * 32;   // uniform -> scalar path
#pragma unroll
            for (int oc = 0; oc < 27; oc++)
                acc[oc] = fmaf(xv[k], wr[oc], acc[oc]);
        }
    }

    // reduce across the 4 csub lanes (adjacent lanes)
#pragma unroll
    for (int oc = 0; oc < 27; oc++) {
        acc[oc] += __shfl_xor(acc[oc], 1, 64);
        acc[oc] += __shfl_xor(acc[oc], 2, 64);
    }

    if (csub == 0) {
        int pix = yy * W_ + xx;
        float* offo = ws + OFF_BUF + (size_t)b * 18 * HW;
#pragma unroll
        for (int oc = 0; oc < 18; oc++) {
            float v = fminf(fmaxf(acc[oc], -32.f), 32.f);   // max_offset = 128/4
            offo[oc * HW + pix] = v;
        }
        float* msko = ws + MASK_BUF + (size_t)b * 9 * HW;
#pragma unroll
        for (int oc = 0; oc < 9; oc++) {
            float s = 2.f / (1.f + __expf(-acc[18 + oc]));
            msko[oc * HW + pix] = s;
        }
    }
}

// deformable conv via bf16 MFMA:
//   per 16x16-pixel tile, per tap: gather val[p][c] (bilinear*mask) -> bf16 LDS
//   (XOR-swizzled), then D[p][o] += val[p][c] x w[c][o] with mfma 16x16x32.
__global__ __launch_bounds__(256) void deform(const float* __restrict__ x,
                                              const float* __restrict__ ws,
                                              float* __restrict__ out) {
    __shared__ unsigned short val_lds[256 * 64];   // 32 KB, row = pixel (128 B)
    char* ldsb = (char*)val_lds;

    int t = threadIdx.x;
    int b = blockIdx.z;
    int p = t;                         // gather pixel (tile row-major)
    int tx = p & 15, ty = p >> 4;
    int xx = blockIdx.x * 16 + tx;
    int yy = blockIdx.y * 16 + ty;
    int pix = yy * W_ + xx;

    const float* xb   = x + (size_t)b * C_ * HW;
    const float* offp = ws + OFF_BUF  + (size_t)b * 18 * HW + pix;
    const float* mskp = ws + MASK_BUF + (size_t)b * 9  * HW + pix;
    const s16x8* wbf  = (const s16x8*)(ws + WBF_BUF);

    int wv = t >> 6, l = t & 63;
    int lhi = l >> 4, llo = l & 15;

    f32x4 acc[4][4];
#pragma unroll
    for (int mt = 0; mt < 4; mt++)
#pragma unroll
        for (int nt = 0; nt < 4; nt++) acc[mt][nt] = (f32x4)0.f;

    for (int tap = 0; tap < 9; tap++) {
        int kyy = tap / 3, kxx = tap % 3;
        float dy = offp[(2 * tap) * HW];
        float dx = offp[(2 * tap + 1) * HW];
        float m  = mskp[tap * HW];

        float py = (float)(yy + kyy - 1) + dy;
        float px = (float)(xx + kxx - 1) + dx;
        float fy = floorf(py), fx = floorf(px);
        int y0 = (int)fy, x0 = (int)fx;
        float wy = py - fy, wx = px - fx;

        bool vy0 = (y0 >= 0) && (y0 < H_);
        bool vy1 = (y0 + 1 >= 0) && (y0 + 1 < H_);
        bool vx0 = (x0 >= 0) && (x0 < W_);
        bool vx1 = (x0 + 1 >= 0) && (x0 + 1 < W_);
        int yc0 = min(max(y0, 0), H_ - 1);
        int yc1 = min(max(y0 + 1, 0), H_ - 1);
        int xc0 = min(max(x0, 0), W_ - 1);
        int xc1 = min(max(x0 + 1, 0), W_ - 1);

        float e00 = (1.f - wy) * (1.f - wx) * m * ((vy0 && vx0) ? 1.f : 0.f);
        float e01 = (1.f - wy) * wx         * m * ((vy0 && vx1) ? 1.f : 0.f);
        float e10 = wy * (1.f - wx)         * m * ((vy1 && vx0) ? 1.f : 0.f);
        float e11 = wy * wx                 * m * ((vy1 && vx1) ? 1.f : 0.f);

        int i00 = yc0 * W_ + xc0;
        int i01 = yc0 * W_ + xc1;
        int i10 = yc1 * W_ + xc0;
        int i11 = yc1 * W_ + xc1;

        // gather 64 channels, pack bf16 x8, swizzled LDS write
        for (int c0 = 0; c0 < 8; c0++) {
            union { unsigned short u[8]; s16x8 v; } pk;
#pragma unroll
            for (int j = 0; j < 8; j++) {
                const float* xc = xb + (c0 * 8 + j) * HW;
                float v = e00 * xc[i00] + e01 * xc[i01]
                        + e10 * xc[i10] + e11 * xc[i11];
                pk.u[j] = f2bf(v);
            }
            *(s16x8*)(ldsb + p * 128 + ((c0 * 16) ^ ((p & 7) << 4))) = pk.v;
        }
        __syncthreads();

#pragma unroll
        for (int ks = 0; ks < 2; ks++) {
            s16x8 bf[4], af[4];
#pragma unroll
            for (int nt = 0; nt < 4; nt++)
                bf[nt] = wbf[((tap * 2 + ks) * 4 + nt) * 64 + l];
#pragma unroll
            for (int mt = 0; mt < 4; mt++) {
                int pm = (wv * 4 + mt) * 16 + llo;
                af[mt] = *(const s16x8*)(ldsb + pm * 128 +
                          ((ks * 64 + lhi * 16) ^ ((pm & 7) << 4)));
            }
#pragma unroll
            for (int mt = 0; mt < 4; mt++)
#pragma unroll
                for (int nt = 0; nt < 4; nt++)
                    acc[mt][nt] = __builtin_amdgcn_mfma_f32_16x16x32_bf16(
                        af[mt], bf[nt], acc[mt][nt], 0, 0, 0);
        }
        __syncthreads();
    }

    // epilogue: D row = pixel (lhi*4+r within m-tile), col = o (llo)
    float* ob = out + (size_t)b * O_ * HW;
#pragma unroll
    for (int mt = 0; mt < 4; mt++) {
        int tyo = wv * 4 + mt;
        int yyo = blockIdx.y * 16 + tyo;
        int xxo = blockIdx.x * 16 + lhi * 4;
#pragma unroll
        for (int nt = 0; nt < 4; nt++) {
            int o = nt * 16 + llo;
            *(f32x4*)(ob + (size_t)o * HW + yyo * W_ + xxo) = acc[mt][nt];
        }
    }
}

extern "C" void kernel_launch(void* const* d_in, const int* in_sizes, int n_in,
                              void* d_out, int out_size, void* d_ws, size_t ws_size,
                              hipStream_t stream) {
    const float* x    = (const float*)d_in[0];
    const float* offw = (const float*)d_in[1];
    const float* offb = (const float*)d_in[2];
    const float* modw = (const float*)d_in[3];
    const float* modb = (const float*)d_in[4];
    const float* w    = (const float*)d_in[5];
    float* out = (float*)d_out;
    float* ws  = (float*)d_ws;

    int nprep = C_ * KK * 32 + KK * 2 * 4 * 64 * 8;   // 18432 + 36864
    prep_weights<<<dim3((nprep + 255) / 256), dim3(256), 0, stream>>>(offw, modw, w, ws);

    conv_a<<<dim3(W_ / 16, H_ / 4, B_), dim3(256), 0, stream>>>(x, offb, modb, ws);
    deform<<<dim3(W_ / 16, H_ / 16, B_), dim3(256), 0, stream>>>(x, ws, out);
}

// Round 3
// 134.573 us; speedup vs baseline: 9.5057x; 9.5057x over previous
//
#include <hip/hip_runtime.h>
#include <math.h>

#define B_ 8
#define C_ 64
#define H_ 128
#define W_ 128
#define O_ 64
#define HW (H_*W_)

typedef float f32x4 __attribute__((ext_vector_type(4)));
typedef short s16x8 __attribute__((ext_vector_type(8)));

// ws layout (float offsets)
#define OFF_BUF  0              // 8*18*16384 = 2359296 f
#define MASK_BUF 2359296        // 8*9*16384  = 1179648 f
#define XT_BUF   3538944        // NHWC bf16 x: 8*16384*64 us = 4194304 f
#define WBFA_BUF 7733248        // conv B-frags: 18432 us = 9216 f
#define WBFB_BUF 7742464        // deform B-frags: 36864 us = 18432 f
// total 7760896 floats = 29.6 MiB

__device__ __forceinline__ unsigned short f2bf(float f) {
    union { float f; unsigned u; } v; v.f = f;
    unsigned r = (v.u + 0x7FFFu + ((v.u >> 16) & 1u)) >> 16;  // RNE
    return (unsigned short)r;
}
__device__ __forceinline__ float bfelem(s16x8 v, int j) {
    union { unsigned u; float f; } c;
    c.u = ((unsigned)(unsigned short)v[j]) << 16;
    return c.f;
}
__device__ __forceinline__ unsigned cvt_pk_bf16(float lo, float hi) {
    unsigned r;
    asm("v_cvt_pk_bf16_f32 %0, %1, %2" : "=v"(r) : "v"(lo), "v"(hi));
    return r;
}

// Pack weight B-fragments (bf16) for mfma_f32_16x16x32_bf16:
//  B[k=c][n=oc], lane l holds c = ks*32 + (l>>4)*8 + j, oc = nt*16 + (l&15).
//  wbfA: [tap][ks2][nt2][lane][8]   (27 conv outputs, padded to 32)
//  wbfB: [tap][ks2][nt4][lane][8]   (64 deform outputs)
__global__ void prep_weights(const float* __restrict__ offw,
                             const float* __restrict__ modw,
                             const float* __restrict__ w,
                             float* __restrict__ ws) {
    int t = blockIdx.x * 256 + threadIdx.x;
    unsigned short* wbfA = (unsigned short*)(ws + WBFA_BUF);
    unsigned short* wbfB = (unsigned short*)(ws + WBFB_BUF);
    if (t < 18432) {
        int j = t & 7, lane = (t >> 3) & 63, nt = (t >> 9) & 1, ks = (t >> 10) & 1, tap = t >> 11;
        int c = ks * 32 + ((lane >> 4) & 3) * 8 + j;
        int oc = nt * 16 + (lane & 15);
        float v = 0.f;
        if (oc < 18)      v = offw[oc * (C_ * 9) + c * 9 + tap];
        else if (oc < 27) v = modw[(oc - 18) * (C_ * 9) + c * 9 + tap];
        wbfA[t] = f2bf(v);
    } else {
        int t2 = t - 18432;
        if (t2 < 36864) {
            int j = t2 & 7, lane = (t2 >> 3) & 63, nt = (t2 >> 9) & 3, ks = (t2 >> 11) & 1, tap = t2 >> 12;
            int c = ks * 32 + ((lane >> 4) & 3) * 8 + j;
            int o = nt * 16 + (lane & 15);
            wbfB[t2] = f2bf(w[o * (C_ * 9) + c * 9 + tap]);
        }
    }
}

// x NCHW fp32 -> x_t NHWC bf16 (rows of 64 ch = 128B)
__global__ __launch_bounds__(256) void transpose_x(const float* __restrict__ x,
                                                   float* __restrict__ ws) {
    __shared__ float lds[64 * 65];
    int b = blockIdx.y;
    int p0 = blockIdx.x * 64;
    int t = threadIdx.x;
    int pl = t & 63;
    const float* xb = x + (size_t)b * C_ * HW + p0;
#pragma unroll
    for (int i = 0; i < 16; i++) {
        int c = (t >> 6) + i * 4;
        lds[c * 65 + pl] = xb[(size_t)c * HW + pl];
    }
    __syncthreads();
    unsigned short* xo = (unsigned short*)(ws + XT_BUF) + ((size_t)b * HW + p0) * 64;
#pragma unroll
    for (int pass = 0; pass < 2; pass++) {
        int p = (t >> 3) + pass * 32;
        int c0 = (t & 7) * 8;
        union { unsigned short u[8]; s16x8 v; } pk;
#pragma unroll
        for (int j = 0; j < 8; j++) pk.u[j] = f2bf(lds[(c0 + j) * 65 + p]);
        *(s16x8*)(xo + (size_t)p * 64 + c0) = pk.v;
    }
}

// 3x3 conv (27 ch) via MFMA: wave owns 16 consecutive pixels (one row segment).
// A-frags loaded directly from x_t (per-lane 16B), zeroed for OOB taps.
__global__ __launch_bounds__(256) void conv_mfma(const float* __restrict__ offb,
                                                 const float* __restrict__ modb,
                                                 float* __restrict__ ws) {
    int t = threadIdx.x;
    int wv = t >> 6, l = t & 63;
    int b = blockIdx.y;
    int pw = blockIdx.x * 64 + wv * 16;   // wave pixel base (row-aligned: 128%16==0)
    int y = pw >> 7, x0 = pw & 127;
    int pl = l & 15, csub = l >> 4;

    const unsigned short* xtb = (const unsigned short*)(ws + XT_BUF) + (size_t)b * HW * 64;
    const s16x8* wbfA = (const s16x8*)(ws + WBFA_BUF);

    int oc0 = pl, oc1 = 16 + pl;
    float bi0 = offb[oc0];
    float bi1 = (oc1 < 18) ? offb[oc1] : (oc1 < 27 ? modb[oc1 - 18] : 0.f);
    f32x4 acc0 = {bi0, bi0, bi0, bi0};
    f32x4 acc1 = {bi1, bi1, bi1, bi1};
    const s16x8 zf = {0, 0, 0, 0, 0, 0, 0, 0};

    for (int tap = 0; tap < 9; tap++) {
        int ys = y + tap / 3 - 1;
        int xs = x0 + pl + tap % 3 - 1;
        bool vld = ((unsigned)ys < (unsigned)H_) && ((unsigned)xs < (unsigned)W_);
        int yc = min(max(ys, 0), H_ - 1);
        int xc = min(max(xs, 0), W_ - 1);
        const unsigned short* rp = xtb + (size_t)(yc * W_ + xc) * 64 + csub * 8;
        s16x8 a0 = *(const s16x8*)rp;          // c = csub*8+j        (ks=0)
        s16x8 a1 = *(const s16x8*)(rp + 32);   // c = 32 + csub*8+j   (ks=1)
        a0 = vld ? a0 : zf;
        a1 = vld ? a1 : zf;
        s16x8 b00 = wbfA[((tap * 2 + 0) * 2 + 0) * 64 + l];
        s16x8 b01 = wbfA[((tap * 2 + 0) * 2 + 1) * 64 + l];
        s16x8 b10 = wbfA[((tap * 2 + 1) * 2 + 0) * 64 + l];
        s16x8 b11 = wbfA[((tap * 2 + 1) * 2 + 1) * 64 + l];
        acc0 = __builtin_amdgcn_mfma_f32_16x16x32_bf16(a0, b00, acc0, 0, 0, 0);
        acc1 = __builtin_amdgcn_mfma_f32_16x16x32_bf16(a0, b01, acc1, 0, 0, 0);
        acc0 = __builtin_amdgcn_mfma_f32_16x16x32_bf16(a1, b10, acc0, 0, 0, 0);
        acc1 = __builtin_amdgcn_mfma_f32_16x16x32_bf16(a1, b11, acc1, 0, 0, 0);
    }

    // D: row (pixel) = csub*4+j, col (oc) = pl | 16+pl
    float* offo = ws + OFF_BUF + (size_t)b * 18 * HW;
    float* msko = ws + MASK_BUF + (size_t)b * 9 * HW;
    int gp0 = pw + csub * 4;
    {
        f32x4 v;
#pragma unroll
        for (int j = 0; j < 4; j++) v[j] = fminf(fmaxf(acc0[j], -32.f), 32.f);
        *(f32x4*)(offo + (size_t)oc0 * HW + gp0) = v;
    }
    if (oc1 < 18) {
        f32x4 v;
#pragma unroll
        for (int j = 0; j < 4; j++) v[j] = fminf(fmaxf(acc1[j], -32.f), 32.f);
        *(f32x4*)(offo + (size_t)oc1 * HW + gp0) = v;
    } else if (oc1 < 27) {
        f32x4 v;
#pragma unroll
        for (int j = 0; j < 4; j++) v[j] = 2.f / (1.f + __expf(-acc1[j]));
        *(f32x4*)(msko + (size_t)(oc1 - 18) * HW + gp0) = v;
    }
}

// deform: wave owns 16 pixels; lane = (pixel pl, 16-ch chunk csub).
// Gather 4 corners from NHWC bf16, combine fp32, pack bf16, transpose through
// wave-private XOR-swizzled LDS, 8 MFMAs per tap. No __syncthreads needed.
__global__ __launch_bounds__(256) void deform(float* __restrict__ ws,
                                              float* __restrict__ out) {
    __shared__ char vlds[4][2048];
    int t = threadIdx.x;
    int wv = t >> 6, l = t & 63;
    char* myv = vlds[wv];
    int b = blockIdx.y;
    int pw = blockIdx.x * 64 + wv * 16;
    int y = pw >> 7, x0 = pw & 127;
    int pl = l & 15, csub = l >> 4;
    int xx = x0 + pl;
    int swz = (pl & 7) << 4;

    const unsigned short* xtb = (const unsigned short*)(ws + XT_BUF) + (size_t)b * HW * 64;
    const s16x8* wbfB = (const s16x8*)(ws + WBFB_BUF);
    const float* offp = ws + OFF_BUF  + (size_t)b * 18 * HW + pw + pl;
    const float* mskp = ws + MASK_BUF + (size_t)b * 9  * HW + pw + pl;

    f32x4 acc[4];
#pragma unroll
    for (int nt = 0; nt < 4; nt++) acc[nt] = (f32x4)0.f;

    for (int tap = 0; tap < 9; tap++) {
        float dy = offp[(2 * tap) * HW];
        float dx = offp[(2 * tap + 1) * HW];
        float mm = mskp[tap * HW];
        float py = (float)(y + tap / 3 - 1) + dy;
        float px = (float)(xx + tap % 3 - 1) + dx;
        float fy = floorf(py), fx = floorf(px);
        int y0 = (int)fy, xq = (int)fx;
        float wy = py - fy, wx = px - fx;
        bool vy0 = (unsigned)y0 < (unsigned)H_;
        bool vy1 = (unsigned)(y0 + 1) < (unsigned)H_;
        bool vx0 = (unsigned)xq < (unsigned)W_;
        bool vx1 = (unsigned)(xq + 1) < (unsigned)W_;
        int yc0 = min(max(y0, 0), H_ - 1), yc1 = min(max(y0 + 1, 0), H_ - 1);
        int xc0 = min(max(xq, 0), W_ - 1), xc1 = min(max(xq + 1, 0), W_ - 1);
        float e00 = (1.f - wy) * (1.f - wx) * mm * ((vy0 && vx0) ? 1.f : 0.f);
        float e01 = (1.f - wy) * wx         * mm * ((vy0 && vx1) ? 1.f : 0.f);
        float e10 = wy * (1.f - wx)         * mm * ((vy1 && vx0) ? 1.f : 0.f);
        float e11 = wy * wx                 * mm * ((vy1 && vx1) ? 1.f : 0.f);

        const unsigned short* p00 = xtb + (size_t)(yc0 * W_ + xc0) * 64 + csub * 16;
        const unsigned short* p01 = xtb + (size_t)(yc0 * W_ + xc1) * 64 + csub * 16;
        const unsigned short* p10 = xtb + (size_t)(yc1 * W_ + xc0) * 64 + csub * 16;
        const unsigned short* p11 = xtb + (size_t)(yc1 * W_ + xc1) * 64 + csub * 16;
        s16x8 c00a = *(const s16x8*)p00, c00b = *(const s16x8*)(p00 + 8);
        s16x8 c01a = *(const s16x8*)p01, c01b = *(const s16x8*)(p01 + 8);
        s16x8 c10a = *(const s16x8*)p10, c10b = *(const s16x8*)(p10 + 8);
        s16x8 c11a = *(const s16x8*)p11, c11b = *(const s16x8*)(p11 + 8);

        float val[16];
#pragma unroll
        for (int j = 0; j < 8; j++) {
            val[j]     = e00 * bfelem(c00a, j) + e01 * bfelem(c01a, j)
                       + e10 * bfelem(c10a, j) + e11 * bfelem(c11a, j);
            val[8 + j] = e00 * bfelem(c00b, j) + e01 * bfelem(c01b, j)
                       + e10 * bfelem(c10b, j) + e11 * bfelem(c11b, j);
        }
        union { unsigned u[4]; s16x8 v; } pk0, pk1;
#pragma unroll
        for (int i = 0; i < 4; i++) {
            pk0.u[i] = cvt_pk_bf16(val[2 * i], val[2 * i + 1]);
            pk1.u[i] = cvt_pk_bf16(val[8 + 2 * i], val[9 + 2 * i]);
        }
        // wave-private LDS transpose: row = pixel (128B), byte ^= (row&7)<<4
        *(s16x8*)(myv + pl * 128 + ((csub * 32)      ^ swz)) = pk0.v;
        *(s16x8*)(myv + pl * 128 + ((csub * 32 + 16) ^ swz)) = pk1.v;
        asm volatile("s_waitcnt lgkmcnt(0)" ::: "memory");
        s16x8 a0 = *(const s16x8*)(myv + pl * 128 + ((csub * 16)      ^ swz));  // ks=0
        s16x8 a1 = *(const s16x8*)(myv + pl * 128 + ((64 + csub * 16) ^ swz));  // ks=1

#pragma unroll
        for (int nt = 0; nt < 4; nt++) {
            s16x8 bf0 = wbfB[((tap * 2 + 0) * 4 + nt) * 64 + l];
            s16x8 bf1 = wbfB[((tap * 2 + 1) * 4 + nt) * 64 + l];
            acc[nt] = __builtin_amdgcn_mfma_f32_16x16x32_bf16(a0, bf0, acc[nt], 0, 0, 0);
            acc[nt] = __builtin_amdgcn_mfma_f32_16x16x32_bf16(a1, bf1, acc[nt], 0, 0, 0);
        }
    }

    float* ob = out + (size_t)b * O_ * HW;
    int gp0 = pw + csub * 4;
#pragma unroll
    for (int nt = 0; nt < 4; nt++) {
        int oc = nt * 16 + pl;
        *(f32x4*)(ob + (size_t)oc * HW + gp0) = acc[nt];
    }
}

extern "C" void kernel_launch(void* const* d_in, const int* in_sizes, int n_in,
                              void* d_out, int out_size, void* d_ws, size_t ws_size,
                              hipStream_t stream) {
    const float* x    = (const float*)d_in[0];
    const float* offw = (const float*)d_in[1];
    const float* offb = (const float*)d_in[2];
    const float* modw = (const float*)d_in[3];
    const float* modb = (const float*)d_in[4];
    const float* w    = (const float*)d_in[5];
    float* out = (float*)d_out;
    float* ws  = (float*)d_ws;

    prep_weights<<<dim3(216), dim3(256), 0, stream>>>(offw, modw, w, ws);
    transpose_x<<<dim3(HW / 64, B_), dim3(256), 0, stream>>>(x, ws);
    conv_mfma<<<dim3(HW / 64, B_), dim3(256), 0, stream>>>(offb, modb, ws);
    deform<<<dim3(HW / 64, B_), dim3(256), 0, stream>>>(ws, out);
}

// Round 5
// 128.330 us; speedup vs baseline: 9.9682x; 1.0486x over previous
//
#include <hip/hip_runtime.h>
#include <math.h>

#define B_ 8
#define C_ 64
#define H_ 128
#define W_ 128
#define O_ 64
#define HW (H_*W_)

typedef float f32x4 __attribute__((ext_vector_type(4)));
typedef short s16x8 __attribute__((ext_vector_type(8)));

// ws layout (float offsets)
#define OFF_BUF  0              // 8*18*16384 = 2359296 f
#define MASK_BUF 2359296        // 8*9*16384  = 1179648 f
#define XT_BUF   3538944        // NHWC bf16 x: 8*16384*64 us = 4194304 f
#define WBFA_BUF 7733248        // conv B-frags: 18432 us = 9216 f
#define WBFB_BUF 7742464        // deform B-frags: 36864 us = 18432 f

__device__ __forceinline__ unsigned short f2bf(float f) {
    union { float f; unsigned u; } v; v.f = f;
    unsigned r = (v.u + 0x7FFFu + ((v.u >> 16) & 1u)) >> 16;  // RNE
    return (unsigned short)r;
}
__device__ __forceinline__ float bfel(s16x8 v, int j) {
    union { unsigned u; float f; } c;
    c.u = ((unsigned)(unsigned short)v[j]) << 16;
    return c.f;
}
__device__ __forceinline__ unsigned cvt_pk_bf16(float lo, float hi) {
    unsigned r;
    asm("v_cvt_pk_bf16_f32 %0, %1, %2" : "=v"(r) : "v"(lo), "v"(hi));
    return r;
}

// B-fragments (bf16) for mfma_f32_16x16x32_bf16:
//  B[k=c][n=oc], lane l holds c = ks*32 + (l>>4)*8 + j, oc = nt*16 + (l&15).
__global__ void prep_weights(const float* __restrict__ offw,
                             const float* __restrict__ modw,
                             const float* __restrict__ w,
                             float* __restrict__ ws) {
    int t = blockIdx.x * 256 + threadIdx.x;
    unsigned short* wbfA = (unsigned short*)(ws + WBFA_BUF);
    unsigned short* wbfB = (unsigned short*)(ws + WBFB_BUF);
    if (t < 18432) {
        int j = t & 7, lane = (t >> 3) & 63, nt = (t >> 9) & 1, ks = (t >> 10) & 1, tap = t >> 11;
        int c = ks * 32 + ((lane >> 4) & 3) * 8 + j;
        int oc = nt * 16 + (lane & 15);
        float v = 0.f;
        if (oc < 18)      v = offw[oc * (C_ * 9) + c * 9 + tap];
        else if (oc < 27) v = modw[(oc - 18) * (C_ * 9) + c * 9 + tap];
        wbfA[t] = f2bf(v);
    } else {
        int t2 = t - 18432;
        if (t2 < 36864) {
            int j = t2 & 7, lane = (t2 >> 3) & 63, nt = (t2 >> 9) & 3, ks = (t2 >> 11) & 1, tap = t2 >> 12;
            int c = ks * 32 + ((lane >> 4) & 3) * 8 + j;
            int o = nt * 16 + (lane & 15);
            wbfB[t2] = f2bf(w[o * (C_ * 9) + c * 9 + tap]);
        }
    }
}

// x NCHW fp32 -> x_t NHWC bf16 (rows of 64 ch = 128B)
__global__ __launch_bounds__(256) void transpose_x(const float* __restrict__ x,
                                                   float* __restrict__ ws) {
    __shared__ float lds[64 * 65];
    int b = blockIdx.y;
    int p0 = blockIdx.x * 64;
    int t = threadIdx.x;
    int pl = t & 63;
    const float* xb = x + (size_t)b * C_ * HW + p0;
#pragma unroll
    for (int i = 0; i < 16; i++) {
        int c = (t >> 6) + i * 4;
        lds[c * 65 + pl] = xb[(size_t)c * HW + pl];
    }
    __syncthreads();
    unsigned short* xo = (unsigned short*)(ws + XT_BUF) + ((size_t)b * HW + p0) * 64;
#pragma unroll
    for (int pass = 0; pass < 2; pass++) {
        int p = (t >> 3) + pass * 32;
        int c0 = (t & 7) * 8;
        union { unsigned short u[8]; s16x8 v; } pk;
#pragma unroll
        for (int j = 0; j < 8; j++) pk.u[j] = f2bf(lds[(c0 + j) * 65 + p]);
        *(s16x8*)(xo + (size_t)p * 64 + c0) = pk.v;
    }
}

// 3x3 conv (27 ch) via MFMA: wave owns 16 consecutive pixels.  (round-3 exact)
__global__ __launch_bounds__(256) void conv_mfma(const float* __restrict__ offb,
                                                 const float* __restrict__ modb,
                                                 float* __restrict__ ws) {
    int t = threadIdx.x;
    int wv = t >> 6, l = t & 63;
    int b = blockIdx.y;
    int pw = blockIdx.x * 64 + wv * 16;
    int y = pw >> 7, x0 = pw & 127;
    int pl = l & 15, csub = l >> 4;

    const unsigned short* xtb = (const unsigned short*)(ws + XT_BUF) + (size_t)b * HW * 64;
    const s16x8* wbfA = (const s16x8*)(ws + WBFA_BUF);

    int oc0 = pl, oc1 = 16 + pl;
    float bi0 = offb[oc0];
    float bi1 = (oc1 < 18) ? offb[oc1] : (oc1 < 27 ? modb[oc1 - 18] : 0.f);
    f32x4 acc0 = {bi0, bi0, bi0, bi0};
    f32x4 acc1 = {bi1, bi1, bi1, bi1};
    const s16x8 zf = {0, 0, 0, 0, 0, 0, 0, 0};

    for (int tap = 0; tap < 9; tap++) {
        int ys = y + tap / 3 - 1;
        int xs = x0 + pl + tap % 3 - 1;
        bool vld = ((unsigned)ys < (unsigned)H_) && ((unsigned)xs < (unsigned)W_);
        int yc = min(max(ys, 0), H_ - 1);
        int xc = min(max(xs, 0), W_ - 1);
        const unsigned short* rp = xtb + (size_t)(yc * W_ + xc) * 64 + csub * 8;
        s16x8 a0 = *(const s16x8*)rp;
        s16x8 a1 = *(const s16x8*)(rp + 32);
        a0 = vld ? a0 : zf;
        a1 = vld ? a1 : zf;
        s16x8 b00 = wbfA[((tap * 2 + 0) * 2 + 0) * 64 + l];
        s16x8 b01 = wbfA[((tap * 2 + 0) * 2 + 1) * 64 + l];
        s16x8 b10 = wbfA[((tap * 2 + 1) * 2 + 0) * 64 + l];
        s16x8 b11 = wbfA[((tap * 2 + 1) * 2 + 1) * 64 + l];
        acc0 = __builtin_amdgcn_mfma_f32_16x16x32_bf16(a0, b00, acc0, 0, 0, 0);
        acc1 = __builtin_amdgcn_mfma_f32_16x16x32_bf16(a0, b01, acc1, 0, 0, 0);
        acc0 = __builtin_amdgcn_mfma_f32_16x16x32_bf16(a1, b10, acc0, 0, 0, 0);
        acc1 = __builtin_amdgcn_mfma_f32_16x16x32_bf16(a1, b11, acc1, 0, 0, 0);
    }

    float* offo = ws + OFF_BUF + (size_t)b * 18 * HW;
    float* msko = ws + MASK_BUF + (size_t)b * 9 * HW;
    int gp0 = pw + csub * 4;
    {
        f32x4 v;
#pragma unroll
        for (int j = 0; j < 4; j++) v[j] = fminf(fmaxf(acc0[j], -32.f), 32.f);
        *(f32x4*)(offo + (size_t)oc0 * HW + gp0) = v;
    }
    if (oc1 < 18) {
        f32x4 v;
#pragma unroll
        for (int j = 0; j < 4; j++) v[j] = fminf(fmaxf(acc1[j], -32.f), 32.f);
        *(f32x4*)(offo + (size_t)oc1 * HW + gp0) = v;
    } else if (oc1 < 27) {
        f32x4 v;
#pragma unroll
        for (int j = 0; j < 4; j++) v[j] = 2.f / (1.f + __expf(-acc1[j]));
        *(f32x4*)(msko + (size_t)(oc1 - 18) * HW + gp0) = v;
    }
}

// deform: no LDS, per-lane in-register A-fragments, straight-line tap loop.
// Lane (pl,csub) gathers channels csub*8+j (ks=0) and 32+csub*8+j (ks=1) of
// pixel pw+pl with its own bilinear coords -> exactly the MFMA A-fragment.
__global__ __launch_bounds__(256) void deform(const float* __restrict__ ws,
                                              float* __restrict__ out) {
    int t = threadIdx.x;
    int wv = t >> 6, l = t & 63;
    int b = blockIdx.y;
    int pw = blockIdx.x * 64 + wv * 16;
    int y = pw >> 7, x0 = pw & 127;
    int pl = l & 15, csub = l >> 4;
    int xx = x0 + pl;

    const unsigned short* xtb = (const unsigned short*)(ws + XT_BUF) + (size_t)b * HW * 64;
    const s16x8* wbfB = (const s16x8*)(ws + WBFB_BUF);
    const float* offp = ws + OFF_BUF  + (size_t)b * 18 * HW + pw + pl;
    const float* mskp = ws + MASK_BUF + (size_t)b * 9  * HW + pw + pl;

    // hoist all offset/mask loads (independent of the gather chain)
    float dyv[9], dxv[9], mmv[9];
#pragma unroll
    for (int tap = 0; tap < 9; tap++) {
        dyv[tap] = offp[(2 * tap) * HW];
        dxv[tap] = offp[(2 * tap + 1) * HW];
        mmv[tap] = mskp[tap * HW];
    }

    f32x4 acc[4];
#pragma unroll
    for (int nt = 0; nt < 4; nt++) acc[nt] = (f32x4)0.f;

#pragma unroll
    for (int tap = 0; tap < 9; tap++) {
        float py = (float)(y + tap / 3 - 1) + dyv[tap];
        float px = (float)(xx + tap % 3 - 1) + dxv[tap];
        float mm = mmv[tap];
        float fy = floorf(py), fx = floorf(px);
        int y0 = (int)fy, xq = (int)fx;
        float wy = py - fy, wx = px - fx;
        bool vy0 = (unsigned)y0 < (unsigned)H_;
        bool vy1 = (unsigned)(y0 + 1) < (unsigned)H_;
        bool vx0 = (unsigned)xq < (unsigned)W_;
        bool vx1 = (unsigned)(xq + 1) < (unsigned)W_;
        int yc0 = min(max(y0, 0), H_ - 1), yc1 = min(max(y0 + 1, 0), H_ - 1);
        int xc0 = min(max(xq, 0), W_ - 1), xc1 = min(max(xq + 1, 0), W_ - 1);
        float e0 = (1.f - wy) * (1.f - wx) * mm * ((vy0 && vx0) ? 1.f : 0.f);
        float e1 = (1.f - wy) * wx         * mm * ((vy0 && vx1) ? 1.f : 0.f);
        float e2 = wy * (1.f - wx)         * mm * ((vy1 && vx0) ? 1.f : 0.f);
        float e3 = wy * wx                 * mm * ((vy1 && vx1) ? 1.f : 0.f);

        const unsigned short* p00 = xtb + (size_t)(yc0 * W_ + xc0) * 64 + csub * 8;
        const unsigned short* p01 = xtb + (size_t)(yc0 * W_ + xc1) * 64 + csub * 8;
        const unsigned short* p10 = xtb + (size_t)(yc1 * W_ + xc0) * 64 + csub * 8;
        const unsigned short* p11 = xtb + (size_t)(yc1 * W_ + xc1) * 64 + csub * 8;
        s16x8 g00a = *(const s16x8*)p00, g00b = *(const s16x8*)(p00 + 32);
        s16x8 g01a = *(const s16x8*)p01, g01b = *(const s16x8*)(p01 + 32);
        s16x8 g10a = *(const s16x8*)p10, g10b = *(const s16x8*)(p10 + 32);
        s16x8 g11a = *(const s16x8*)p11, g11b = *(const s16x8*)(p11 + 32);

        float va[8], vb[8];
#pragma unroll
        for (int j = 0; j < 8; j++) {
            va[j] = e0 * bfel(g00a, j) + e1 * bfel(g01a, j)
                  + e2 * bfel(g10a, j) + e3 * bfel(g11a, j);
            vb[j] = e0 * bfel(g00b, j) + e1 * bfel(g01b, j)
                  + e2 * bfel(g10b, j) + e3 * bfel(g11b, j);
        }
        union { unsigned u[4]; s16x8 v; } A0, A1;
#pragma unroll
        for (int i = 0; i < 4; i++) {
            A0.u[i] = cvt_pk_bf16(va[2 * i], va[2 * i + 1]);
            A1.u[i] = cvt_pk_bf16(vb[2 * i], vb[2 * i + 1]);
        }
#pragma unroll
        for (int nt = 0; nt < 4; nt++) {
            s16x8 bf0 = wbfB[((tap * 2 + 0) * 4 + nt) * 64 + l];
            s16x8 bf1 = wbfB[((tap * 2 + 1) * 4 + nt) * 64 + l];
            acc[nt] = __builtin_amdgcn_mfma_f32_16x16x32_bf16(A0.v, bf0, acc[nt], 0, 0, 0);
            acc[nt] = __builtin_amdgcn_mfma_f32_16x16x32_bf16(A1.v, bf1, acc[nt], 0, 0, 0);
        }
    }

    float* ob = out + (size_t)b * O_ * HW;
    int gp0 = pw + csub * 4;
#pragma unroll
    for (int nt = 0; nt < 4; nt++) {
        int oc = nt * 16 + pl;
        *(f32x4*)(ob + (size_t)oc * HW + gp0) = acc[nt];
    }
}

extern "C" void kernel_launch(void* const* d_in, const int* in_sizes, int n_in,
                              void* d_out, int out_size, void* d_ws, size_t ws_size,
                              hipStream_t stream) {
    const float* x    = (const float*)d_in[0];
    const float* offw = (const float*)d_in[1];
    const float* offb = (const float*)d_in[2];
    const float* modw = (const float*)d_in[3];
    const float* modb = (const float*)d_in[4];
    const float* w    = (const float*)d_in[5];
    float* out = (float*)d_out;
    float* ws  = (float*)d_ws;

    prep_weights<<<dim3(216), dim3(256), 0, stream>>>(offw, modw, w, ws);
    transpose_x<<<dim3(HW / 64, B_), dim3(256), 0, stream>>>(x, ws);
    conv_mfma<<<dim3(HW / 64, B_), dim3(256), 0, stream>>>(offb, modb, ws);
    deform<<<dim3(HW / 64, B_), dim3(256), 0, stream>>>(ws, out);
}

// Round 6
// 127.449 us; speedup vs baseline: 10.0371x; 1.0069x over previous
//
#include <hip/hip_runtime.h>
#include <math.h>

#define B_ 8
#define C_ 64
#define H_ 128
#define W_ 128
#define O_ 64
#define HW (H_*W_)

typedef float f32x4 __attribute__((ext_vector_type(4)));
typedef short s16x8 __attribute__((ext_vector_type(8)));

// ws layout (float offsets)
#define OFF_BUF  0              // 8*18*16384 = 2359296 f
#define MASK_BUF 2359296        // 8*9*16384  = 1179648 f
#define XT_BUF   3538944        // NHWC bf16 x: 8*16384*64 us = 4194304 f
#define WBFA_BUF 7733248        // conv B-frags: 18432 us = 9216 f
#define WBFB_BUF 7742464        // deform B-frags: 36864 us = 18432 f

__device__ __forceinline__ unsigned short f2bf(float f) {
    union { float f; unsigned u; } v; v.f = f;
    unsigned r = (v.u + 0x7FFFu + ((v.u >> 16) & 1u)) >> 16;  // RNE
    return (unsigned short)r;
}
__device__ __forceinline__ float bfel(s16x8 v, int j) {
    union { unsigned u; float f; } c;
    c.u = ((unsigned)(unsigned short)v[j]) << 16;
    return c.f;
}
__device__ __forceinline__ unsigned cvt_pk_bf16(float lo, float hi) {
    unsigned r;
    asm("v_cvt_pk_bf16_f32 %0, %1, %2" : "=v"(r) : "v"(lo), "v"(hi));
    return r;
}

// XCD-aware block remap: linear dispatch id mod 8 == blockIdx.x mod 8 -> batch,
// so each XCD's L2 caches exactly one batch's x_t + off/mask. Bijective.
__device__ __forceinline__ void remap_block(int& b, int& chunk) {
    b = blockIdx.x & 7;
    chunk = (blockIdx.y << 5) | (blockIdx.x >> 3);
}

// B-fragments (bf16) for mfma_f32_16x16x32_bf16:
//  B[k=c][n=oc], lane l holds c = ks*32 + (l>>4)*8 + j, oc = nt*16 + (l&15).
__global__ void prep_weights(const float* __restrict__ offw,
                             const float* __restrict__ modw,
                             const float* __restrict__ w,
                             float* __restrict__ ws) {
    int t = blockIdx.x * 256 + threadIdx.x;
    unsigned short* wbfA = (unsigned short*)(ws + WBFA_BUF);
    unsigned short* wbfB = (unsigned short*)(ws + WBFB_BUF);
    if (t < 18432) {
        int j = t & 7, lane = (t >> 3) & 63, nt = (t >> 9) & 1, ks = (t >> 10) & 1, tap = t >> 11;
        int c = ks * 32 + ((lane >> 4) & 3) * 8 + j;
        int oc = nt * 16 + (lane & 15);
        float v = 0.f;
        if (oc < 18)      v = offw[oc * (C_ * 9) + c * 9 + tap];
        else if (oc < 27) v = modw[(oc - 18) * (C_ * 9) + c * 9 + tap];
        wbfA[t] = f2bf(v);
    } else {
        int t2 = t - 18432;
        if (t2 < 36864) {
            int j = t2 & 7, lane = (t2 >> 3) & 63, nt = (t2 >> 9) & 3, ks = (t2 >> 11) & 1, tap = t2 >> 12;
            int c = ks * 32 + ((lane >> 4) & 3) * 8 + j;
            int o = nt * 16 + (lane & 15);
            wbfB[t2] = f2bf(w[o * (C_ * 9) + c * 9 + tap]);
        }
    }
}

// x NCHW fp32 -> x_t NHWC bf16 (rows of 64 ch = 128B)
__global__ __launch_bounds__(256) void transpose_x(const float* __restrict__ x,
                                                   float* __restrict__ ws) {
    __shared__ float lds[64 * 65];
    int b, chunk;
    remap_block(b, chunk);
    int p0 = chunk * 64;
    int t = threadIdx.x;
    int pl = t & 63;
    const float* xb = x + (size_t)b * C_ * HW + p0;
#pragma unroll
    for (int i = 0; i < 16; i++) {
        int c = (t >> 6) + i * 4;
        lds[c * 65 + pl] = xb[(size_t)c * HW + pl];
    }
    __syncthreads();
    unsigned short* xo = (unsigned short*)(ws + XT_BUF) + ((size_t)b * HW + p0) * 64;
#pragma unroll
    for (int pass = 0; pass < 2; pass++) {
        int p = (t >> 3) + pass * 32;
        int c0 = (t & 7) * 8;
        union { unsigned short u[8]; s16x8 v; } pk;
#pragma unroll
        for (int j = 0; j < 8; j++) pk.u[j] = f2bf(lds[(c0 + j) * 65 + p]);
        *(s16x8*)(xo + (size_t)p * 64 + c0) = pk.v;
    }
}

// 3x3 conv (27 ch) via MFMA: wave owns 16 consecutive pixels.
__global__ __launch_bounds__(256) void conv_mfma(const float* __restrict__ offb,
                                                 const float* __restrict__ modb,
                                                 float* __restrict__ ws) {
    int t = threadIdx.x;
    int wv = t >> 6, l = t & 63;
    int b, chunk;
    remap_block(b, chunk);
    int pw = chunk * 64 + wv * 16;
    int y = pw >> 7, x0 = pw & 127;
    int pl = l & 15, csub = l >> 4;

    const unsigned short* xtb = (const unsigned short*)(ws + XT_BUF) + (size_t)b * HW * 64;
    const s16x8* wbfA = (const s16x8*)(ws + WBFA_BUF);

    int oc0 = pl, oc1 = 16 + pl;
    float bi0 = offb[oc0];
    float bi1 = (oc1 < 18) ? offb[oc1] : (oc1 < 27 ? modb[oc1 - 18] : 0.f);
    f32x4 acc0 = {bi0, bi0, bi0, bi0};
    f32x4 acc1 = {bi1, bi1, bi1, bi1};
    const s16x8 zf = {0, 0, 0, 0, 0, 0, 0, 0};

    for (int tap = 0; tap < 9; tap++) {
        int ys = y + tap / 3 - 1;
        int xs = x0 + pl + tap % 3 - 1;
        bool vld = ((unsigned)ys < (unsigned)H_) && ((unsigned)xs < (unsigned)W_);
        int yc = min(max(ys, 0), H_ - 1);
        int xc = min(max(xs, 0), W_ - 1);
        const unsigned short* rp = xtb + (size_t)(yc * W_ + xc) * 64 + csub * 8;
        s16x8 a0 = *(const s16x8*)rp;
        s16x8 a1 = *(const s16x8*)(rp + 32);
        a0 = vld ? a0 : zf;
        a1 = vld ? a1 : zf;
        s16x8 b00 = wbfA[((tap * 2 + 0) * 2 + 0) * 64 + l];
        s16x8 b01 = wbfA[((tap * 2 + 0) * 2 + 1) * 64 + l];
        s16x8 b10 = wbfA[((tap * 2 + 1) * 2 + 0) * 64 + l];
        s16x8 b11 = wbfA[((tap * 2 + 1) * 2 + 1) * 64 + l];
        acc0 = __builtin_amdgcn_mfma_f32_16x16x32_bf16(a0, b00, acc0, 0, 0, 0);
        acc1 = __builtin_amdgcn_mfma_f32_16x16x32_bf16(a0, b01, acc1, 0, 0, 0);
        acc0 = __builtin_amdgcn_mfma_f32_16x16x32_bf16(a1, b10, acc0, 0, 0, 0);
        acc1 = __builtin_amdgcn_mfma_f32_16x16x32_bf16(a1, b11, acc1, 0, 0, 0);
    }

    float* offo = ws + OFF_BUF + (size_t)b * 18 * HW;
    float* msko = ws + MASK_BUF + (size_t)b * 9 * HW;
    int gp0 = pw + csub * 4;
    {
        f32x4 v;
#pragma unroll
        for (int j = 0; j < 4; j++) v[j] = fminf(fmaxf(acc0[j], -32.f), 32.f);
        *(f32x4*)(offo + (size_t)oc0 * HW + gp0) = v;
    }
    if (oc1 < 18) {
        f32x4 v;
#pragma unroll
        for (int j = 0; j < 4; j++) v[j] = fminf(fmaxf(acc1[j], -32.f), 32.f);
        *(f32x4*)(offo + (size_t)oc1 * HW + gp0) = v;
    } else if (oc1 < 27) {
        f32x4 v;
#pragma unroll
        for (int j = 0; j < 4; j++) v[j] = 2.f / (1.f + __expf(-acc1[j]));
        *(f32x4*)(msko + (size_t)(oc1 - 18) * HW + gp0) = v;
    }
}

// ---- deform: per-lane in-register A-fragments, tap-PAIR ILP, no LDS ----
// Straight-line per pair: both taps' 16 gathers issue before either combine
// (counted vmcnt lets tap-A combine overlap tap-B loads). No rotating state.
struct TapG { s16x8 g[8]; float e0, e1, e2, e3; };

__device__ __forceinline__ TapG stage(int tap, int y, int xx,
                                      float dy, float dx, float mm,
                                      const unsigned short* __restrict__ xtb, int csub) {
    TapG s;
    float py = (float)(y + tap / 3 - 1) + dy;
    float px = (float)(xx + tap % 3 - 1) + dx;
    float fy = floorf(py), fx = floorf(px);
    int y0 = (int)fy, xq = (int)fx;
    float wy = py - fy, wx = px - fx;
    bool vy0 = (unsigned)y0 < (unsigned)H_;
    bool vy1 = (unsigned)(y0 + 1) < (unsigned)H_;
    bool vx0 = (unsigned)xq < (unsigned)W_;
    bool vx1 = (unsigned)(xq + 1) < (unsigned)W_;
    int yc0 = min(max(y0, 0), H_ - 1), yc1 = min(max(y0 + 1, 0), H_ - 1);
    int xc0 = min(max(xq, 0), W_ - 1), xc1 = min(max(xq + 1, 0), W_ - 1);
    s.e0 = (1.f - wy) * (1.f - wx) * mm * ((vy0 && vx0) ? 1.f : 0.f);
    s.e1 = (1.f - wy) * wx         * mm * ((vy0 && vx1) ? 1.f : 0.f);
    s.e2 = wy * (1.f - wx)         * mm * ((vy1 && vx0) ? 1.f : 0.f);
    s.e3 = wy * wx                 * mm * ((vy1 && vx1) ? 1.f : 0.f);
    const unsigned short* p00 = xtb + (size_t)(yc0 * W_ + xc0) * 64 + csub * 8;
    const unsigned short* p01 = xtb + (size_t)(yc0 * W_ + xc1) * 64 + csub * 8;
    const unsigned short* p10 = xtb + (size_t)(yc1 * W_ + xc0) * 64 + csub * 8;
    const unsigned short* p11 = xtb + (size_t)(yc1 * W_ + xc1) * 64 + csub * 8;
    s.g[0] = *(const s16x8*)p00; s.g[1] = *(const s16x8*)(p00 + 32);
    s.g[2] = *(const s16x8*)p01; s.g[3] = *(const s16x8*)(p01 + 32);
    s.g[4] = *(const s16x8*)p10; s.g[5] = *(const s16x8*)(p10 + 32);
    s.g[6] = *(const s16x8*)p11; s.g[7] = *(const s16x8*)(p11 + 32);
    return s;
}

__device__ __forceinline__ void consume(const TapG& s, int tap,
                                        const s16x8* __restrict__ wbfB,
                                        int l, f32x4 acc[4]) {
    float va[8], vb[8];
#pragma unroll
    for (int j = 0; j < 8; j++) {
        va[j] = s.e0 * bfel(s.g[0], j) + s.e1 * bfel(s.g[2], j)
              + s.e2 * bfel(s.g[4], j) + s.e3 * bfel(s.g[6], j);
        vb[j] = s.e0 * bfel(s.g[1], j) + s.e1 * bfel(s.g[3], j)
              + s.e2 * bfel(s.g[5], j) + s.e3 * bfel(s.g[7], j);
    }
    union { unsigned u[4]; s16x8 v; } A0, A1;
#pragma unroll
    for (int i = 0; i < 4; i++) {
        A0.u[i] = cvt_pk_bf16(va[2 * i], va[2 * i + 1]);
        A1.u[i] = cvt_pk_bf16(vb[2 * i], vb[2 * i + 1]);
    }
#pragma unroll
    for (int nt = 0; nt < 4; nt++) {
        s16x8 bf0 = wbfB[((tap * 2 + 0) * 4 + nt) * 64 + l];
        s16x8 bf1 = wbfB[((tap * 2 + 1) * 4 + nt) * 64 + l];
        acc[nt] = __builtin_amdgcn_mfma_f32_16x16x32_bf16(A0.v, bf0, acc[nt], 0, 0, 0);
        acc[nt] = __builtin_amdgcn_mfma_f32_16x16x32_bf16(A1.v, bf1, acc[nt], 0, 0, 0);
    }
}

__global__ __launch_bounds__(256) void deform(const float* __restrict__ ws,
                                              float* __restrict__ out) {
    int t = threadIdx.x;
    int wv = t >> 6, l = t & 63;
    int b, chunk;
    remap_block(b, chunk);
    int pw = chunk * 64 + wv * 16;
    int y = pw >> 7, x0 = pw & 127;
    int pl = l & 15, csub = l >> 4;
    int xx = x0 + pl;

    const unsigned short* xtb = (const unsigned short*)(ws + XT_BUF) + (size_t)b * HW * 64;
    const s16x8* wbfB = (const s16x8*)(ws + WBFB_BUF);
    const float* offp = ws + OFF_BUF  + (size_t)b * 18 * HW + pw + pl;
    const float* mskp = ws + MASK_BUF + (size_t)b * 9  * HW + pw + pl;

    // hoist all offset/mask loads (independent of the gather chains)
    float dyv[9], dxv[9], mmv[9];
#pragma unroll
    for (int tap = 0; tap < 9; tap++) {
        dyv[tap] = offp[(2 * tap) * HW];
        dxv[tap] = offp[(2 * tap + 1) * HW];
        mmv[tap] = mskp[tap * HW];
    }

    f32x4 acc[4];
#pragma unroll
    for (int nt = 0; nt < 4; nt++) acc[nt] = (f32x4)0.f;

#pragma unroll
    for (int pr = 0; pr < 4; pr++) {
        int tA = 2 * pr, tB = 2 * pr + 1;
        TapG sA = stage(tA, y, xx, dyv[tA], dxv[tA], mmv[tA], xtb, csub);
        TapG sB = stage(tB, y, xx, dyv[tB], dxv[tB], mmv[tB], xtb, csub);
        consume(sA, tA, wbfB, l, acc);
        consume(sB, tB, wbfB, l, acc);
    }
    {
        TapG s8 = stage(8, y, xx, dyv[8], dxv[8], mmv[8], xtb, csub);
        consume(s8, 8, wbfB, l, acc);
    }

    float* ob = out + (size_t)b * O_ * HW;
    int gp0 = pw + csub * 4;
#pragma unroll
    for (int nt = 0; nt < 4; nt++) {
        int oc = nt * 16 + pl;
        *(f32x4*)(ob + (size_t)oc * HW + gp0) = acc[nt];
    }
}

extern "C" void kernel_launch(void* const* d_in, const int* in_sizes, int n_in,
                              void* d_out, int out_size, void* d_ws, size_t ws_size,
                              hipStream_t stream) {
    const float* x    = (const float*)d_in[0];
    const float* offw = (const float*)d_in[1];
    const float* offb = (const float*)d_in[2];
    const float* modw = (const float*)d_in[3];
    const float* modb = (const float*)d_in[4];
    const float* w    = (const float*)d_in[5];
    float* out = (float*)d_out;
    float* ws  = (float*)d_ws;

    prep_weights<<<dim3(216), dim3(256), 0, stream>>>(offw, modw, w, ws);
    transpose_x<<<dim3(HW / 64, B_), dim3(256), 0, stream>>>(x, ws);
    conv_mfma<<<dim3(HW / 64, B_), dim3(256), 0, stream>>>(offb, modb, ws);
    deform<<<dim3(HW / 64, B_), dim3(256), 0, stream>>>(ws, out);
}